// Round 1
// baseline (483.935 us; speedup 1.0000x reference)
//
#include <hip/hip_runtime.h>
#include <math.h>

#define B_TOT 32768
#define NPB 4   // batch elements per block, one wave (64 lanes) each

__global__ __launch_bounds__(256) void encoder_kernel(
    const float* __restrict__ x1,
    const float* __restrict__ x2,
    const float* __restrict__ w1, const float* __restrict__ b1,
    const float* __restrict__ w2, const float* __restrict__ b2,
    const float* __restrict__ fcm1_w, const float* __restrict__ fcm1_b,
    const float* __restrict__ fc_w, const float* __restrict__ fc_b,
    float* __restrict__ out)
{
    // block-shared weights
    __shared__ float s_w1[21], s_w2[21];
    __shared__ float s_fcm1w[800], s_fcm1b[10];
    __shared__ float s_fcw[1100], s_fcb[100];
    __shared__ float s_b1, s_b2;
    // per-wave (per-batch) working buffers
    __shared__ __align__(16) float xs[NPB][960];   // x tile (120,4,2)
    __shared__ float p1[NPB][240];                 // pooled conv1 (30,4,2)
    __shared__ float f2[NPB][80];                  // pooled conv2 (10,4,2) flat
    __shared__ float v11[NPB][12];                 // elu(10) + sigmoid

    const int tid = threadIdx.x;
    for (int i = tid; i < 21;   i += 256) { s_w1[i] = w1[i]; s_w2[i] = w2[i]; }
    for (int i = tid; i < 800;  i += 256) s_fcm1w[i] = fcm1_w[i];
    for (int i = tid; i < 10;   i += 256) s_fcm1b[i] = fcm1_b[i];
    for (int i = tid; i < 1100; i += 256) s_fcw[i] = fc_w[i];
    for (int i = tid; i < 100;  i += 256) s_fcb[i] = fc_b[i];
    if (tid == 0) { s_b1 = b1[0]; s_b2 = b2[0]; }

    const int wave = tid >> 6;
    const int lane = tid & 63;
    const long b = (long)blockIdx.x * NPB + wave;

    // output layout (flat float32, tuple concat order)
    const size_t Z0  = 0;                                // z:      B*100
    const size_t XM0 = (size_t)B_TOT * 100;              // aug_xm: B*960
    const size_t SD0 = XM0 + (size_t)B_TOT * 960;        // aug_sd: B
    const size_t P10 = SD0 + (size_t)B_TOT;              // pool1:  B*240
    const size_t P20 = P10 + (size_t)B_TOT * 240;        // pool2:  B*80

    // ---- stage x1[b] into LDS + emit aug_xm copy (float4 coalesced) ----
    {
        const float4* xin  = (const float4*)(x1 + b * 960);
        float4*       xo   = (float4*)(out + XM0 + b * 960);
        float4*       xl   = (float4*)xs[wave];
        #pragma unroll
        for (int t = 0; t < 4; t++) {
            int i = lane + 64 * t;
            if (i < 240) {
                float4 v = xin[i];
                xl[i] = v;
                xo[i] = v;
            }
        }
    }
    __syncthreads();   // weights + x staged

    // ---- conv1 (7,3,1) pad (3,1,0) + ReLU + maxpool D/4 with indices ----
    {
        const float bb = s_b1;
        #pragma unroll
        for (int t = 0; t < 4; t++) {
            int p = lane + 64 * t;          // pooled output (dd,h,w) flat, 240 total
            if (p < 240) {
                int dd = p >> 3, h = (p >> 1) & 3, w = p & 1;
                float best = 0.0f; int bj = 0;
                #pragma unroll
                for (int j = 0; j < 4; j++) {
                    int d = dd * 4 + j;
                    float acc = bb;
                    #pragma unroll
                    for (int kd = 0; kd < 7; kd++) {
                        int dz = d + kd - 3;
                        if (dz >= 0 && dz < 120) {
                            #pragma unroll
                            for (int kh = 0; kh < 3; kh++) {
                                int hz = h + kh - 1;
                                if (hz >= 0 && hz < 4)
                                    acc += xs[wave][(dz * 4 + hz) * 2 + w] * s_w1[kd * 3 + kh];
                            }
                        }
                    }
                    acc = fmaxf(acc, 0.0f);
                    // strict > keeps FIRST occurrence of max (matches jnp.argmax;
                    // ties at exact 0.0 after ReLU are common)
                    if (j == 0 || acc > best) { best = acc; bj = j; }
                }
                p1[wave][p] = best;
                int idx = ((dd * 4 + bj) * 4 + h) * 2 + w;   // flat over (D=120,H,W)
                out[P10 + b * 240 + p] = (float)idx;
            }
        }
    }
    __syncthreads();

    // ---- conv2 + ReLU + maxpool D/3 with indices ----
    {
        const float bb = s_b2;
        #pragma unroll
        for (int t = 0; t < 2; t++) {
            int p = lane + 64 * t;          // 80 pooled outputs
            if (p < 80) {
                int dd = p >> 3, h = (p >> 1) & 3, w = p & 1;
                float best = 0.0f; int bj = 0;
                #pragma unroll
                for (int j = 0; j < 3; j++) {
                    int d = dd * 3 + j;
                    float acc = bb;
                    #pragma unroll
                    for (int kd = 0; kd < 7; kd++) {
                        int dz = d + kd - 3;
                        if (dz >= 0 && dz < 30) {
                            #pragma unroll
                            for (int kh = 0; kh < 3; kh++) {
                                int hz = h + kh - 1;
                                if (hz >= 0 && hz < 4)
                                    acc += p1[wave][(dz * 4 + hz) * 2 + w] * s_w2[kd * 3 + kh];
                            }
                        }
                    }
                    acc = fmaxf(acc, 0.0f);
                    if (j == 0 || acc > best) { best = acc; bj = j; }
                }
                f2[wave][p] = best;
                int idx = ((dd * 3 + bj) * 4 + h) * 2 + w;   // flat over (D=30,H,W)
                out[P20 + b * 80 + p] = (float)idx;
            }
        }
    }
    __syncthreads();

    // ---- fcm1 (80->10) + ELU;  sigmoid(x2);  aug_x_sd copy ----
    if (lane < 10) {
        float acc = s_fcm1b[lane];
        #pragma unroll 8
        for (int i = 0; i < 80; i++)
            acc += f2[wave][i] * s_fcm1w[lane * 80 + i];
        v11[wave][lane] = (acc > 0.0f) ? acc : expm1f(acc);
    } else if (lane == 10) {
        float xv = x2[b];
        v11[wave][10] = 1.0f / (1.0f + expf(-xv));
        out[SD0 + b] = xv;
    }
    __syncthreads();

    // ---- fc (11->100) + BatchNorm-eval scale ----
    {
        const float scale = 1.0f / sqrtf(1.0f + 1e-5f);
        #pragma unroll
        for (int t = 0; t < 2; t++) {
            int o = lane + 64 * t;
            if (o < 100) {
                float acc = s_fcb[o];
                #pragma unroll
                for (int i = 0; i < 11; i++)
                    acc += v11[wave][i] * s_fcw[o * 11 + i];
                out[Z0 + b * 100 + o] = acc * scale;
            }
        }
    }
}

extern "C" void kernel_launch(void* const* d_in, const int* in_sizes, int n_in,
                              void* d_out, int out_size, void* d_ws, size_t ws_size,
                              hipStream_t stream) {
    const float* x1     = (const float*)d_in[0];
    const float* x2     = (const float*)d_in[1];
    // d_in[2] shifts, d_in[3] nonzero_mask_xm: unused in eval-mode forward
    const float* w1     = (const float*)d_in[4];
    const float* b1     = (const float*)d_in[5];
    const float* w2     = (const float*)d_in[6];
    const float* b2     = (const float*)d_in[7];
    const float* fcm1_w = (const float*)d_in[8];
    const float* fcm1_b = (const float*)d_in[9];
    const float* fc_w   = (const float*)d_in[10];
    const float* fc_b   = (const float*)d_in[11];
    float* out = (float*)d_out;

    dim3 grid(B_TOT / NPB), block(256);
    encoder_kernel<<<grid, block, 0, stream>>>(x1, x2, w1, b1, w2, b2,
                                               fcm1_w, fcm1_b, fc_w, fc_b, out);
}

// Round 2
// 350.104 us; speedup vs baseline: 1.3823x; 1.3823x over previous
//
#include <hip/hip_runtime.h>
#include <math.h>

#define B_TOT 32768
#define NPB 4                 // one wave = one batch element, 4 per block

// padded x buffer: [w][hz+1][dz+3], row stride 127 (odd -> 2-way max bank alias)
#define XS_RS 127
#define XS_WS (6 * XS_RS)     // 762
#define XS_SZ (2 * XS_WS)     // 1524 floats / wave
// padded pool1 buffer: [w][hz+1][dz+3], D=30 -> cols 36, stride 37 (odd)
#define P_RS 37
#define P_WS (6 * P_RS)       // 222
#define P_SZ 448              // 444 rounded up to float4 multiple

// wave-level sync: buffers are wave-private; avoid s_barrier's vmcnt(0) drain
__device__ __forceinline__ void wave_sync() {
    __builtin_amdgcn_s_waitcnt(0xC07F);    // lgkmcnt(0) only (vm/exp left pending)
    __builtin_amdgcn_wave_barrier();
}

__global__ __launch_bounds__(256) void encoder_kernel(
    const float* __restrict__ x1, const float* __restrict__ x2,
    const float* __restrict__ w1, const float* __restrict__ b1,
    const float* __restrict__ w2, const float* __restrict__ b2,
    const float* __restrict__ fcm1_w, const float* __restrict__ fcm1_b,
    const float* __restrict__ fc_w, const float* __restrict__ fc_b,
    float* __restrict__ out)
{
    __shared__ float s_fcm1w[10 * 81];               // stride 81 (odd-ish) kills 5-way alias
    __shared__ __align__(16) float xs[NPB][XS_SZ];
    __shared__ __align__(16) float p1[NPB][P_SZ];
    __shared__ float f2[NPB][80];
    __shared__ float v11[NPB][12];

    const int tid  = threadIdx.x;
    const int wave = tid >> 6, lane = tid & 63;
    const long b   = (long)blockIdx.x * NPB + wave;

    // output layout (flat f32, tuple order: z, aug_xm, aug_x_sd, pool1_idx, pool2_idx)
    const size_t XM0 = (size_t)B_TOT * 100;
    const size_t SD0 = XM0 + (size_t)B_TOT * 960;
    const size_t P10 = SD0 + (size_t)B_TOT;
    const size_t P20 = P10 + (size_t)B_TOT * 240;

    // ---- stage fcm1 weights to LDS (cross-wave; the only true barrier) ----
    for (int i = tid; i < 800; i += 256)
        s_fcm1w[(i / 80) * 81 + (i % 80)] = fcm1_w[i];
    __syncthreads();

    // ---- conv weights via compile-time-indexed uniform loads -> SGPRs ----
    float w1r[21], w2r[21];
    #pragma unroll
    for (int k = 0; k < 21; k++) { w1r[k] = w1[k]; w2r[k] = w2[k]; }
    const float bb1 = b1[0], bb2 = b2[0];

    // ---- zero the padded buffers (float4), then scatter-stage x1 ----
    {
        const float4 z4 = make_float4(0.f, 0.f, 0.f, 0.f);
        float4* xz = (float4*)xs[wave];
        #pragma unroll
        for (int t = 0; t < 6; t++) { int i = lane + 64 * t; if (i < XS_SZ / 4) xz[i] = z4; }
        float4* pz = (float4*)p1[wave];
        #pragma unroll
        for (int t = 0; t < 2; t++) { int i = lane + 64 * t; if (i < P_SZ / 4) pz[i] = z4; }
    }
    // DS ops from one wave complete in order; no sync needed before overwrite,
    // but keep one for compiler-ordering safety:
    wave_sync();

    {
        const float4* xin = (const float4*)(x1 + b * 960);
        float4*       xo  = (float4*)(out + XM0 + b * 960);
        #pragma unroll
        for (int t = 0; t < 4; t++) {
            int i = lane + 64 * t;             // 240 float4 per batch
            if (i < 240) {
                float4 v = xin[i];
                xo[i] = v;                     // aug_xm copy
                float vv[4] = {v.x, v.y, v.z, v.w};
                #pragma unroll
                for (int c = 0; c < 4; c++) {
                    int e = i * 4 + c, d = e >> 3, h = (e >> 1) & 3, w = e & 1;
                    xs[wave][w * XS_WS + (h + 1) * XS_RS + d + 3] = vv[c];
                }
            }
        }
    }
    wave_sync();

    // ---- conv1 (7,3,1) pad(3,1,0) + ReLU + maxpool D/4 (+indices) ----
    #pragma unroll
    for (int t = 0; t < 4; t++) {
        int p = lane + 64 * t;                 // 240 pooled outputs
        if (p < 240) {
            int dd = p >> 3, h = (p >> 1) & 3, w = p & 1;
            int d0 = dd * 4;
            const float* base = &xs[wave][w * XS_WS + h * XS_RS + d0];
            float vals[3][10];
            #pragma unroll
            for (int r = 0; r < 3; r++)
                #pragma unroll
                for (int c = 0; c < 10; c++)
                    vals[r][c] = base[r * XS_RS + c];
            float best = 0.f; int bj = 0;
            #pragma unroll
            for (int j = 0; j < 4; j++) {
                float acc = bb1;
                #pragma unroll
                for (int kd = 0; kd < 7; kd++)
                    #pragma unroll
                    for (int kh = 0; kh < 3; kh++)
                        acc = fmaf(vals[kh][j + kd], w1r[kd * 3 + kh], acc);
                acc = fmaxf(acc, 0.f);
                if (j == 0)            { best = acc; }
                else if (acc > best)   { best = acc; bj = j; }   // first-max tiebreak
            }
            p1[wave][w * P_WS + (h + 1) * P_RS + dd + 3] = best;
            out[P10 + b * 240 + p] = (float)(((dd * 4 + bj) * 4 + h) * 2 + w);
        }
    }
    wave_sync();

    // ---- conv2 + ReLU + maxpool D/3 (+indices) ----
    #pragma unroll
    for (int t = 0; t < 2; t++) {
        int p = lane + 64 * t;                 // 80 pooled outputs
        if (p < 80) {
            int dd = p >> 3, h = (p >> 1) & 3, w = p & 1;
            int d0 = dd * 3;
            const float* base = &p1[wave][w * P_WS + h * P_RS + d0];
            float vals[3][9];
            #pragma unroll
            for (int r = 0; r < 3; r++)
                #pragma unroll
                for (int c = 0; c < 9; c++)
                    vals[r][c] = base[r * P_RS + c];
            float best = 0.f; int bj = 0;
            #pragma unroll
            for (int j = 0; j < 3; j++) {
                float acc = bb2;
                #pragma unroll
                for (int kd = 0; kd < 7; kd++)
                    #pragma unroll
                    for (int kh = 0; kh < 3; kh++)
                        acc = fmaf(vals[kh][j + kd], w2r[kd * 3 + kh], acc);
                acc = fmaxf(acc, 0.f);
                if (j == 0)            { best = acc; }
                else if (acc > best)   { best = acc; bj = j; }
            }
            f2[wave][p] = best;
            out[P20 + b * 80 + p] = (float)(((dd * 3 + bj) * 4 + h) * 2 + w);
        }
    }
    wave_sync();

    // ---- fc weights -> per-lane regs (late load: short live range) ----
    float fw0[11], fw1[11], fb0, fb1 = 0.f;
    #pragma unroll
    for (int k = 0; k < 11; k++) { fw0[k] = fc_w[lane * 11 + k]; fw1[k] = 0.f; }
    fb0 = fc_b[lane];
    if (lane < 36) {
        #pragma unroll
        for (int k = 0; k < 11; k++) fw1[k] = fc_w[(64 + lane) * 11 + k];
        fb1 = fc_b[64 + lane];
    }

    // ---- fcm1 (80->10, split 4-way) + ELU;  sigmoid(x2) ----
    if (lane < 40) {
        int o = lane >> 2, q = lane & 3;
        float acc = 0.f;
        #pragma unroll
        for (int k = 0; k < 20; k++) {
            int i = q * 20 + k;
            acc = fmaf(f2[wave][i], s_fcm1w[o * 81 + i], acc);
        }
        acc += __shfl_xor(acc, 1);
        acc += __shfl_xor(acc, 2);
        if (q == 0) {
            acc += fcm1_b[o];
            v11[wave][o] = (acc > 0.f) ? acc : expm1f(acc);
        }
    } else if (lane == 40) {
        float xv = x2[b];
        v11[wave][10] = 1.f / (1.f + expf(-xv));
        out[SD0 + b] = xv;
    }
    wave_sync();

    // ---- fc (11->100) + BN-eval scale ----
    {
        const float scale = 0.9999950000374997f;   // 1/sqrt(1+1e-5)
        float vv[11];
        #pragma unroll
        for (int i = 0; i < 11; i++) vv[i] = v11[wave][i];  // broadcast, conflict-free
        float a0 = fb0;
        #pragma unroll
        for (int i = 0; i < 11; i++) a0 = fmaf(vv[i], fw0[i], a0);
        out[b * 100 + lane] = a0 * scale;
        if (lane < 36) {
            float a1 = fb1;
            #pragma unroll
            for (int i = 0; i < 11; i++) a1 = fmaf(vv[i], fw1[i], a1);
            out[b * 100 + 64 + lane] = a1 * scale;
        }
    }
}

extern "C" void kernel_launch(void* const* d_in, const int* in_sizes, int n_in,
                              void* d_out, int out_size, void* d_ws, size_t ws_size,
                              hipStream_t stream) {
    const float* x1     = (const float*)d_in[0];
    const float* x2     = (const float*)d_in[1];
    const float* w1     = (const float*)d_in[4];
    const float* b1     = (const float*)d_in[5];
    const float* w2     = (const float*)d_in[6];
    const float* b2     = (const float*)d_in[7];
    const float* fcm1_w = (const float*)d_in[8];
    const float* fcm1_b = (const float*)d_in[9];
    const float* fc_w   = (const float*)d_in[10];
    const float* fc_b   = (const float*)d_in[11];
    float* out = (float*)d_out;

    dim3 grid(B_TOT / NPB), block(256);
    encoder_kernel<<<grid, block, 0, stream>>>(x1, x2, w1, b1, w2, b2,
                                               fcm1_w, fcm1_b, fc_w, fc_b, out);
}